// Round 5
// baseline (718.698 us; speedup 1.0000x reference)
//
#include <hip/hip_runtime.h>

#define NN 100000
#define IC 128
#define OC 64
#define NE 1000000

#define NBUCK 256
#define BN 391          // nodes per bucket; 256*391 = 100096 >= NN
#define RCAP 5120       // bucket region capacity (mean 3906, +19 sigma)
#define SEGCAP 8192     // csr segment LDS capacity (mean 3906, +69 sigma)
#define EPB 2048        // edges per binning block
#define CAPA 32         // LDS buffer entries per bucket in k_binA

typedef __attribute__((ext_vector_type(8))) short short8;
typedef __attribute__((ext_vector_type(4))) float f32x4;

static __device__ __forceinline__ float b2f(unsigned short u) {
    unsigned v = ((unsigned)u) << 16;
    float f;
    __builtin_memcpy(&f, &v, 4);
    return f;
}
static __device__ __forceinline__ unsigned short f2b(float f) {
    unsigned u;
    __builtin_memcpy(&u, &f, 4);
    u += 0x7fff + ((u >> 16) & 1);
    return (unsigned short)(u >> 16);
}

// ---------------- CSR build pass A: bin edges into 256 dst-range buckets ----------------
// packed entry: (dst_local << 17) | src   (dst_local < 391 -> 9 bits, src < 2^17)
__global__ __launch_bounds__(256) void k_binA(const int* __restrict__ src,
                                              const int* __restrict__ dst,
                                              int* __restrict__ gcur,
                                              unsigned* __restrict__ bins) {
    __shared__ unsigned buf[NBUCK][CAPA];
    __shared__ int lcnt[NBUCK];
    const int t = threadIdx.x;
    lcnt[t] = 0;
    __syncthreads();
    const int e0 = blockIdx.x * EPB;
#pragma unroll
    for (int q = 0; q < EPB / 256; ++q) {
        int e = e0 + q * 256 + t;
        if (e < NE) {
            int d = dst[e];
            int s = src[e];
            int b = d / BN;
            unsigned packed = ((unsigned)(d - b * BN) << 17) | (unsigned)s;
            int idx = atomicAdd(&lcnt[b], 1);
            if (idx < CAPA) {
                buf[b][idx] = packed;
            } else {  // overflow slow path (p ~ 1e-12 per bucket-block)
                int g = atomicAdd(&gcur[b], 1);
                if (g < RCAP) bins[(size_t)b * RCAP + g] = packed;
            }
        }
    }
    __syncthreads();
    // coalesced flush: one wave per bucket (round-robin)
    const int wid = t >> 6, lane = t & 63;
    for (int b = wid; b < NBUCK; b += 4) {
        int c = lcnt[b];
        if (c > CAPA) c = CAPA;
        if (c > 0) {
            int g = 0;
            if (lane == 0) g = atomicAdd(&gcur[b], c);
            g = __shfl(g, 0, 64);
            for (int i = lane; i < c; i += 64)
                if (g + i < RCAP) bins[(size_t)b * RCAP + g + i] = buf[b][i];
        }
    }
}

// ---------------- CSR build: exclusive scan of bucket counts ----------------
__global__ __launch_bounds__(256) void k_bscan(const int* __restrict__ gcur,
                                               int* __restrict__ bstart,
                                               int* __restrict__ row_ptr) {
    __shared__ int sh[NBUCK];
    const int t = threadIdx.x;
    int v = gcur[t];
    if (v > RCAP) v = RCAP;
    sh[t] = v;
    __syncthreads();
    for (int off = 1; off < NBUCK; off <<= 1) {
        int u = (t >= off) ? sh[t - off] : 0;
        __syncthreads();
        sh[t] += u;
        __syncthreads();
    }
    bstart[t] = sh[t] - v;
    if (t == NBUCK - 1) row_ptr[NN] = sh[t];
}

// ---------------- CSR build pass B: per-bucket count + scan + place (all coalesced) ----------------
__global__ __launch_bounds__(256) void k_binB(const int* __restrict__ gcur,
                                              const int* __restrict__ bstart,
                                              const unsigned* __restrict__ bins,
                                              int* __restrict__ row_ptr,
                                              int* __restrict__ csr) {
    __shared__ int lc[512];    // counts -> exclusive starts
    __shared__ int tsum[256];
    __shared__ int rk[512];
    __shared__ int seg[SEGCAP];
    const int b = blockIdx.x;
    const int t = threadIdx.x;
    const int base = b * BN;
    const int nloc = (NN - base < BN) ? (NN - base) : BN;
    lc[t] = 0; lc[t + 256] = 0;
    rk[t] = 0; rk[t + 256] = 0;
    __syncthreads();
    int c = gcur[b];
    if (c > RCAP) c = RCAP;
    const unsigned* mybins = bins + (size_t)b * RCAP;
    for (int i = t; i < c; i += 256) atomicAdd(&lc[mybins[i] >> 17], 1);
    __syncthreads();
    // exclusive scan of lc[0..511]: 2 items/thread + block scan of thread sums
    int a0 = lc[2 * t], a1 = lc[2 * t + 1];
    int s = a0 + a1;
    tsum[t] = s;
    __syncthreads();
    for (int off = 1; off < 256; off <<= 1) {
        int u = (t >= off) ? tsum[t - off] : 0;
        __syncthreads();
        tsum[t] += u;
        __syncthreads();
    }
    int pre = tsum[t] - s;
    lc[2 * t] = pre;
    lc[2 * t + 1] = pre + a0;
    __syncthreads();
    const int bs = bstart[b];
    for (int i = t; i < nloc; i += 256) row_ptr[base + i] = bs + lc[i];
    if (c <= SEGCAP) {
        for (int i = t; i < c; i += 256) {
            unsigned p = mybins[i];
            int dl = p >> 17;
            int r = atomicAdd(&rk[dl], 1);
            seg[lc[dl] + r] = (int)(p & 0x1FFFFu);
        }
        __syncthreads();
        for (int i = t; i < c; i += 256) csr[bs + i] = seg[i];
    } else {  // fallback: direct scatter (p ~ 0)
        for (int i = t; i < c; i += 256) {
            unsigned p = mybins[i];
            int dl = p >> 17;
            int r = atomicAdd(&rk[dl], 1);
            csr[bs + lc[dl] + r] = (int)(p & 0x1FFFFu);
        }
    }
}

// ---------------- x fp32 -> bf16 ----------------
__global__ __launch_bounds__(256) void k_cvt(const float* __restrict__ x,
                                             unsigned short* __restrict__ xb) {
    int t = blockIdx.x * 256 + threadIdx.x;
    if (t >= NN * IC / 8) return;
    const float4* p = (const float4*)x + (size_t)t * 2;
    float4 f0 = p[0], f1 = p[1];
    short8 o;
    o[0] = (short)f2b(f0.x); o[1] = (short)f2b(f0.y);
    o[2] = (short)f2b(f0.z); o[3] = (short)f2b(f0.w);
    o[4] = (short)f2b(f1.x); o[5] = (short)f2b(f1.y);
    o[6] = (short)f2b(f1.z); o[7] = (short)f2b(f1.w);
    *((short8*)xb + t) = o;
}

// ---------------- weight prep: stack [Wl;Wr] (K=256), transpose to col-major bf16 ----------------
__global__ __launch_bounds__(256) void k_wprep(
    const float* __restrict__ W1l, const float* __restrict__ W1r,
    const float* __restrict__ Wml, const float* __restrict__ Wmr,
    const float* __restrict__ Wsl, const float* __restrict__ Wsr,
    unsigned short* __restrict__ Wt1, unsigned short* __restrict__ Wt2) {
    int t = blockIdx.x * 256 + threadIdx.x;
    if (t >= 2 * 128 * 256) return;
    int layer = t >> 15;
    int rem = t & 32767;
    int col = rem >> 8;
    int k = rem & 255;
    float v;
    if (layer == 0) {
        v = (k < 128) ? W1l[k * 128 + col] : W1r[(k - 128) * 128 + col];
        Wt1[col * 256 + k] = f2b(v);
    } else {
        if (col < OC) v = (k < 128) ? Wml[k * OC + col] : Wmr[(k - 128) * OC + col];
        else {
            int c2 = col - OC;
            v = (k < 128) ? Wsl[k * OC + c2] : Wsr[(k - 128) * OC + c2];
        }
        Wt2[col * 256 + k] = f2b(v);
    }
}

// ---------------- gather mean-aggregation (bf16 in/out, f32 accum) ----------------
// one wave per node; 4 slots x 16 lanes x 16B; 2-deep neighbor unroll for MLP.
__global__ __launch_bounds__(256) void k_agg(const unsigned short* __restrict__ feat,
                                             const int* __restrict__ row_ptr,
                                             const int* __restrict__ csr,
                                             unsigned short* __restrict__ agg) {
    int node = blockIdx.x * 4 + (threadIdx.x >> 6);
    if (node >= NN) return;
    const int lane = threadIdx.x & 63;
    const int slot = lane >> 4;
    const int cg = lane & 15;
    const int beg = row_ptr[node];
    const int end = row_ptr[node + 1];
    float acc[8];
#pragma unroll
    for (int q = 0; q < 8; ++q) acc[q] = 0.f;

    int j = beg + slot;
    for (; j + 4 < end; j += 8) {
        int s1 = csr[j];
        int s2 = csr[j + 4];
        short8 v1 = *(const short8*)(feat + (size_t)s1 * IC + cg * 8);
        short8 v2 = *(const short8*)(feat + (size_t)s2 * IC + cg * 8);
#pragma unroll
        for (int q = 0; q < 8; ++q)
            acc[q] += b2f((unsigned short)v1[q]) + b2f((unsigned short)v2[q]);
    }
    if (j < end) {
        int s1 = csr[j];
        short8 v1 = *(const short8*)(feat + (size_t)s1 * IC + cg * 8);
#pragma unroll
        for (int q = 0; q < 8; ++q) acc[q] += b2f((unsigned short)v1[q]);
    }
#pragma unroll
    for (int q = 0; q < 8; ++q) {
        acc[q] += __shfl_xor(acc[q], 16, 64);
        acc[q] += __shfl_xor(acc[q], 32, 64);
    }
    if (slot == 0) {
        float inv = 1.0f / fmaxf((float)(end - beg), 1.0f);
        short8 o;
#pragma unroll
        for (int q = 0; q < 8; ++q) o[q] = (short)f2b(acc[q] * inv);
        *(short8*)(agg + (size_t)node * IC + cg * 8) = o;
    }
}

// ---------------- MFMA SAGE GEMM: out = [Agg | X] @ Wt + b ----------------
template <int MODE>
__global__ __launch_bounds__(256) void k_gemm(
    const unsigned short* __restrict__ Agg, const unsigned short* __restrict__ Xb,
    const unsigned short* __restrict__ Wt,
    const float* __restrict__ bias0, const float* __restrict__ bias1,
    unsigned short* __restrict__ hout, float* __restrict__ out_mu,
    float* __restrict__ out_ls) {
    const int lane = threadIdx.x & 63;
    const int wid = threadIdx.x >> 6;
    const int rowb = blockIdx.x * 128 + wid * 32;
    const int r16 = lane & 15;
    const int k8 = (lane >> 4) * 8;

    f32x4 acc[2][8];
#pragma unroll
    for (int m = 0; m < 2; ++m)
#pragma unroll
        for (int nt = 0; nt < 8; ++nt) acc[m][nt] = (f32x4){0.f, 0.f, 0.f, 0.f};

    int rA[2];
#pragma unroll
    for (int m = 0; m < 2; ++m) {
        int r = rowb + m * 16 + r16;
        rA[m] = (r < NN) ? r : (NN - 1);
    }

#pragma unroll
    for (int ks = 0; ks < 8; ++ks) {
        const int kbase = ks * 32;
        const unsigned short* Ah = (kbase < 128) ? Agg : Xb;
        const int koff = (kbase & 127) + k8;
        short8 aF[2];
        aF[0] = *(const short8*)(Ah + (size_t)rA[0] * IC + koff);
        aF[1] = *(const short8*)(Ah + (size_t)rA[1] * IC + koff);
#pragma unroll
        for (int nt = 0; nt < 8; ++nt) {
            short8 bF = *(const short8*)(Wt + (nt * 16 + r16) * 256 + kbase + k8);
            acc[0][nt] = __builtin_amdgcn_mfma_f32_16x16x32_bf16(aF[0], bF, acc[0][nt], 0, 0, 0);
            acc[1][nt] = __builtin_amdgcn_mfma_f32_16x16x32_bf16(aF[1], bF, acc[1][nt], 0, 0, 0);
        }
    }

    const int rbase = (lane >> 4) * 4;
#pragma unroll
    for (int m = 0; m < 2; ++m) {
#pragma unroll
        for (int nt = 0; nt < 8; ++nt) {
            const int c = nt * 16 + r16;
            const float bv = (MODE == 0) ? bias0[c] : (c < OC ? bias0[c] : bias1[c - OC]);
#pragma unroll
            for (int r = 0; r < 4; ++r) {
                const int row = rowb + m * 16 + rbase + r;
                if (row >= NN) continue;
                float v = acc[m][nt][r] + bv;
                if (MODE == 0) {
                    v = fmaxf(v, 0.f);
                    hout[(size_t)row * IC + c] = f2b(v);
                } else {
                    if (c < OC) out_mu[(size_t)row * OC + c] = v;
                    else        out_ls[(size_t)row * OC + (c - OC)] = v;
                }
            }
        }
    }
}

extern "C" void kernel_launch(void* const* d_in, const int* in_sizes, int n_in,
                              void* d_out, int out_size, void* d_ws, size_t ws_size,
                              hipStream_t stream) {
    const float* x   = (const float*)d_in[0];
    const int*   ei  = (const int*)d_in[1];
    const float* W1l = (const float*)d_in[2];
    const float* W1r = (const float*)d_in[3];
    const float* b1  = (const float*)d_in[4];
    const float* Wml = (const float*)d_in[5];
    const float* Wmr = (const float*)d_in[6];
    const float* bm  = (const float*)d_in[7];
    const float* Wsl = (const float*)d_in[8];
    const float* Wsr = (const float*)d_in[9];
    const float* bs  = (const float*)d_in[10];

    const int* src = ei;
    const int* dst = ei + NE;

    // workspace layout (bytes)
    char* w = (char*)d_ws;
    unsigned short* xb   = (unsigned short*)(w);                 // 25,600,000
    unsigned short* hb   = (unsigned short*)(w + 25600000);      // 25,600,000
    unsigned short* aggb = (unsigned short*)(w + 51200000);      // 25,600,000
    unsigned short* Wt1  = (unsigned short*)(w + 76800000);      // 65,536
    unsigned short* Wt2  = (unsigned short*)(w + 76865536);      // 65,536
    int* row_ptr  = (int*)(w + 76931072);                        // 400,064 (padded)
    int* csr      = (int*)(w + 77331136);                        // 4,000,000
    int* gcur     = (int*)(w + 81331136);                        // 1,024
    int* bstart   = (int*)(w + 81332160);                        // 1,024
    unsigned* bins = (unsigned*)(w + 81333184);                  // 256*5120*4 = 5,242,880 -> end ~86.6 MB

    float* out_mu = (float*)d_out;
    float* out_ls = out_mu + (size_t)NN * OC;

    const int gemm_grid = (NN + 127) / 128;
    const int agg_grid = (NN + 3) / 4;
    const int binA_grid = (NE + EPB - 1) / EPB;

    // ---- CSR build (shared by both layers) ----
    hipMemsetAsync(gcur, 0, NBUCK * sizeof(int), stream);
    k_binA<<<binA_grid, 256, 0, stream>>>(src, dst, gcur, bins);
    k_bscan<<<1, NBUCK, 0, stream>>>(gcur, bstart, row_ptr);
    k_binB<<<NBUCK, 256, 0, stream>>>(gcur, bstart, bins, row_ptr, csr);

    // conversions / weight prep
    k_cvt<<<(NN * IC / 8 + 255) / 256, 256, 0, stream>>>(x, xb);
    k_wprep<<<(2 * 128 * 256 + 255) / 256, 256, 0, stream>>>(W1l, W1r, Wml, Wmr, Wsl, Wsr, Wt1, Wt2);

    // layer 1
    k_agg<<<agg_grid, 256, 0, stream>>>(xb, row_ptr, csr, aggb);
    k_gemm<0><<<gemm_grid, 256, 0, stream>>>(aggb, xb, Wt1, b1, nullptr,
                                             hb, nullptr, nullptr);

    // layer 2 (shared aggregation feeds mu and logstd)
    k_agg<<<agg_grid, 256, 0, stream>>>(hb, row_ptr, csr, aggb);
    k_gemm<1><<<gemm_grid, 256, 0, stream>>>(aggb, hb, Wt2, bm, bs,
                                             nullptr, out_mu, out_ls);
}

// Round 6
// 264.933 us; speedup vs baseline: 2.7128x; 2.7128x over previous
//
#include <hip/hip_runtime.h>

#define NN 100000
#define IC 128
#define OC 64
#define NE 1000000

#define NBUCK 64
#define BN 1568         // nodes per bucket; 64*1568 = 100352 >= NN
#define RCAP 18432      // bucket region capacity (mean 15625, +22 sigma)
#define EPB 2048        // edges per binning block
#define CAPA 64         // LDS buffer entries per bucket in k_binA (mean 32/chunk)
#define GPAD 16         // gcur padding: one counter per 64B line

typedef __attribute__((ext_vector_type(8))) short short8;
typedef __attribute__((ext_vector_type(4))) float f32x4;

static __device__ __forceinline__ float b2f(unsigned short u) {
    unsigned v = ((unsigned)u) << 16;
    float f;
    __builtin_memcpy(&f, &v, 4);
    return f;
}
static __device__ __forceinline__ unsigned short f2b(float f) {
    unsigned u;
    __builtin_memcpy(&u, &f, 4);
    u += 0x7fff + ((u >> 16) & 1);
    return (unsigned short)(u >> 16);
}

// ---------------- CSR pass A: partition edges into 64 dst-range buckets ----------------
// packed entry: (dst_local << 17) | src   (dst_local < 1568 -> 11 bits, src < 2^17)
__global__ __launch_bounds__(256) void k_binA(const int* __restrict__ src,
                                              const int* __restrict__ dst,
                                              int* __restrict__ gcur,
                                              unsigned* __restrict__ bins) {
    __shared__ unsigned buf[NBUCK][CAPA];  // 16 KB
    __shared__ int lcnt[NBUCK];
    const int t = threadIdx.x;
    if (t < NBUCK) lcnt[t] = 0;
    __syncthreads();
    const int e0 = blockIdx.x * EPB;
#pragma unroll
    for (int q = 0; q < EPB / 256; ++q) {
        int e = e0 + q * 256 + t;
        if (e < NE) {
            int d = dst[e];
            int s = src[e];
            int b = d / BN;
            unsigned packed = ((unsigned)(d - b * BN) << 17) | (unsigned)s;
            int idx = atomicAdd(&lcnt[b], 1);
            if (idx < CAPA) {
                buf[b][idx] = packed;
            } else {  // overflow slow path (expected ~0.1 events per launch)
                int g = atomicAdd(&gcur[b * GPAD], 1);
                if (g < RCAP) bins[(size_t)b * RCAP + g] = packed;
            }
        }
    }
    __syncthreads();
    // coalesced flush: 4 waves x 16 buckets each; one padded-line atomic per bucket
    const int wid = t >> 6, lane = t & 63;
    for (int b = wid * 16; b < wid * 16 + 16; ++b) {
        int c = lcnt[b];
        if (c > CAPA) c = CAPA;
        if (c > 0) {
            int g = 0;
            if (lane == 0) g = atomicAdd(&gcur[b * GPAD], c);
            g = __shfl(g, 0, 64);
            if (lane < c && g + lane < RCAP)
                bins[(size_t)b * RCAP + g + lane] = buf[b][lane];
        }
    }
}

// ---------------- CSR: exclusive scan of 64 bucket counts (one wave) ----------------
__global__ __launch_bounds__(64) void k_bscan(const int* __restrict__ gcur,
                                              int* __restrict__ bstart,
                                              int* __restrict__ row_ptr) {
    const int t = threadIdx.x;
    int v = gcur[t * GPAD];
    if (v > RCAP) v = RCAP;
    int s = v;
    for (int off = 1; off < 64; off <<= 1) {
        int u = __shfl_up(s, off, 64);
        if (t >= off) s += u;
    }
    bstart[t] = s - v;
    if (t == 63) row_ptr[NN] = s;
}

// ---------------- CSR pass B: per-bucket hist + scan + place (all coalesced) ----------------
__global__ __launch_bounds__(512) void k_binB(const int* __restrict__ gcur,
                                              const int* __restrict__ bstart,
                                              const unsigned* __restrict__ bins,
                                              int* __restrict__ row_ptr,
                                              int* __restrict__ csr) {
    __shared__ int lc[2048];   // per-node counts -> exclusive starts (BN=1568 padded)
    __shared__ int rk[2048];
    __shared__ int tsum[512];
    __shared__ int seg[RCAP];  // 72 KB staged csr segment
    const int b = blockIdx.x;
    const int t = threadIdx.x;
    const int base = b * BN;
    const int nloc = (NN - base < BN) ? (NN - base) : BN;
    for (int i = t; i < 2048; i += 512) { lc[i] = 0; rk[i] = 0; }
    __syncthreads();
    int c = gcur[b * GPAD];
    if (c > RCAP) c = RCAP;
    const unsigned* mb = bins + (size_t)b * RCAP;
    for (int i = t; i < c; i += 512) atomicAdd(&lc[mb[i] >> 17], 1);
    __syncthreads();
    int loc[4], s = 0;
#pragma unroll
    for (int q = 0; q < 4; ++q) { loc[q] = lc[t * 4 + q]; s += loc[q]; }
    tsum[t] = s;
    __syncthreads();
    for (int off = 1; off < 512; off <<= 1) {
        int u = (t >= off) ? tsum[t - off] : 0;
        __syncthreads();
        tsum[t] += u;
        __syncthreads();
    }
    int run = tsum[t] - s;
#pragma unroll
    for (int q = 0; q < 4; ++q) { lc[t * 4 + q] = run; run += loc[q]; }
    __syncthreads();
    const int bs = bstart[b];
    for (int i = t; i < nloc; i += 512) row_ptr[base + i] = bs + lc[i];
    for (int i = t; i < c; i += 512) {
        unsigned p = mb[i];
        int dl = p >> 17;
        int r = atomicAdd(&rk[dl], 1);
        seg[lc[dl] + r] = (int)(p & 0x1FFFFu);
    }
    __syncthreads();
    for (int i = t; i < c; i += 512) csr[bs + i] = seg[i];
}

// ---------------- x fp32 -> bf16 ----------------
__global__ __launch_bounds__(256) void k_cvt(const float* __restrict__ x,
                                             unsigned short* __restrict__ xb) {
    int t = blockIdx.x * 256 + threadIdx.x;
    if (t >= NN * IC / 8) return;
    const float4* p = (const float4*)x + (size_t)t * 2;
    float4 f0 = p[0], f1 = p[1];
    short8 o;
    o[0] = (short)f2b(f0.x); o[1] = (short)f2b(f0.y);
    o[2] = (short)f2b(f0.z); o[3] = (short)f2b(f0.w);
    o[4] = (short)f2b(f1.x); o[5] = (short)f2b(f1.y);
    o[6] = (short)f2b(f1.z); o[7] = (short)f2b(f1.w);
    *((short8*)xb + t) = o;
}

// ---------------- weight prep: stack [Wl;Wr] (K=256), transpose to col-major bf16 ----------------
__global__ __launch_bounds__(256) void k_wprep(
    const float* __restrict__ W1l, const float* __restrict__ W1r,
    const float* __restrict__ Wml, const float* __restrict__ Wmr,
    const float* __restrict__ Wsl, const float* __restrict__ Wsr,
    unsigned short* __restrict__ Wt1, unsigned short* __restrict__ Wt2) {
    int t = blockIdx.x * 256 + threadIdx.x;
    if (t >= 2 * 128 * 256) return;
    int layer = t >> 15;
    int rem = t & 32767;
    int col = rem >> 8;
    int k = rem & 255;
    float v;
    if (layer == 0) {
        v = (k < 128) ? W1l[k * 128 + col] : W1r[(k - 128) * 128 + col];
        Wt1[col * 256 + k] = f2b(v);
    } else {
        if (col < OC) v = (k < 128) ? Wml[k * OC + col] : Wmr[(k - 128) * OC + col];
        else {
            int c2 = col - OC;
            v = (k < 128) ? Wsl[k * OC + c2] : Wsr[(k - 128) * OC + c2];
        }
        Wt2[col * 256 + k] = f2b(v);
    }
}

// ---------------- gather mean-aggregation: one 16-lane slot per node ----------------
// 4 nodes/wave, 16 nodes/block; 4-deep neighbor unroll for MLP; no cross-lane reduce.
__global__ __launch_bounds__(256) void k_agg(const unsigned short* __restrict__ feat,
                                             const int* __restrict__ row_ptr,
                                             const int* __restrict__ csr,
                                             unsigned short* __restrict__ agg) {
    const int lane = threadIdx.x & 63;
    const int wid = threadIdx.x >> 6;
    const int slot = lane >> 4;
    const int cg = lane & 15;
    const int node = blockIdx.x * 16 + wid * 4 + slot;
    if (node >= NN) return;
    const int beg = row_ptr[node];
    const int end = row_ptr[node + 1];
    float acc[8];
#pragma unroll
    for (int q = 0; q < 8; ++q) acc[q] = 0.f;

    for (int j = beg; j < end; j += 4) {
        const int nl = end - j;
        short8 v[4];
#pragma unroll
        for (int u = 0; u < 4; ++u) {
            if (u < nl) {
                int s = csr[j + u];
                v[u] = *(const short8*)(feat + (size_t)s * IC + cg * 8);
            }
        }
#pragma unroll
        for (int u = 0; u < 4; ++u) {
            if (u < nl) {
#pragma unroll
                for (int q = 0; q < 8; ++q) acc[q] += b2f((unsigned short)v[u][q]);
            }
        }
    }
    float inv = 1.0f / fmaxf((float)(end - beg), 1.0f);
    short8 o;
#pragma unroll
    for (int q = 0; q < 8; ++q) o[q] = (short)f2b(acc[q] * inv);
    *(short8*)(agg + (size_t)node * IC + cg * 8) = o;
}

// ---------------- MFMA SAGE GEMM: out = [Agg | X] @ Wt + b ----------------
template <int MODE>
__global__ __launch_bounds__(256) void k_gemm(
    const unsigned short* __restrict__ Agg, const unsigned short* __restrict__ Xb,
    const unsigned short* __restrict__ Wt,
    const float* __restrict__ bias0, const float* __restrict__ bias1,
    unsigned short* __restrict__ hout, float* __restrict__ out_mu,
    float* __restrict__ out_ls) {
    const int lane = threadIdx.x & 63;
    const int wid = threadIdx.x >> 6;
    const int rowb = blockIdx.x * 128 + wid * 32;
    const int r16 = lane & 15;
    const int k8 = (lane >> 4) * 8;

    f32x4 acc[2][8];
#pragma unroll
    for (int m = 0; m < 2; ++m)
#pragma unroll
        for (int nt = 0; nt < 8; ++nt) acc[m][nt] = (f32x4){0.f, 0.f, 0.f, 0.f};

    int rA[2];
#pragma unroll
    for (int m = 0; m < 2; ++m) {
        int r = rowb + m * 16 + r16;
        rA[m] = (r < NN) ? r : (NN - 1);
    }

#pragma unroll
    for (int ks = 0; ks < 8; ++ks) {
        const int kbase = ks * 32;
        const unsigned short* Ah = (kbase < 128) ? Agg : Xb;
        const int koff = (kbase & 127) + k8;
        short8 aF[2];
        aF[0] = *(const short8*)(Ah + (size_t)rA[0] * IC + koff);
        aF[1] = *(const short8*)(Ah + (size_t)rA[1] * IC + koff);
#pragma unroll
        for (int nt = 0; nt < 8; ++nt) {
            short8 bF = *(const short8*)(Wt + (nt * 16 + r16) * 256 + kbase + k8);
            acc[0][nt] = __builtin_amdgcn_mfma_f32_16x16x32_bf16(aF[0], bF, acc[0][nt], 0, 0, 0);
            acc[1][nt] = __builtin_amdgcn_mfma_f32_16x16x32_bf16(aF[1], bF, acc[1][nt], 0, 0, 0);
        }
    }

    const int rbase = (lane >> 4) * 4;
#pragma unroll
    for (int m = 0; m < 2; ++m) {
#pragma unroll
        for (int nt = 0; nt < 8; ++nt) {
            const int c = nt * 16 + r16;
            const float bv = (MODE == 0) ? bias0[c] : (c < OC ? bias0[c] : bias1[c - OC]);
#pragma unroll
            for (int r = 0; r < 4; ++r) {
                const int row = rowb + m * 16 + rbase + r;
                if (row >= NN) continue;
                float v = acc[m][nt][r] + bv;
                if (MODE == 0) {
                    v = fmaxf(v, 0.f);
                    hout[(size_t)row * IC + c] = f2b(v);
                } else {
                    if (c < OC) out_mu[(size_t)row * OC + c] = v;
                    else        out_ls[(size_t)row * OC + (c - OC)] = v;
                }
            }
        }
    }
}

extern "C" void kernel_launch(void* const* d_in, const int* in_sizes, int n_in,
                              void* d_out, int out_size, void* d_ws, size_t ws_size,
                              hipStream_t stream) {
    const float* x   = (const float*)d_in[0];
    const int*   ei  = (const int*)d_in[1];
    const float* W1l = (const float*)d_in[2];
    const float* W1r = (const float*)d_in[3];
    const float* b1  = (const float*)d_in[4];
    const float* Wml = (const float*)d_in[5];
    const float* Wmr = (const float*)d_in[6];
    const float* bm  = (const float*)d_in[7];
    const float* Wsl = (const float*)d_in[8];
    const float* Wsr = (const float*)d_in[9];
    const float* bs  = (const float*)d_in[10];

    const int* src = ei;
    const int* dst = ei + NE;

    // workspace layout (bytes)
    char* w = (char*)d_ws;
    unsigned short* xb   = (unsigned short*)(w);                 // 25,600,000
    unsigned short* hb   = (unsigned short*)(w + 25600000);      // 25,600,000
    unsigned short* aggb = (unsigned short*)(w + 51200000);      // 25,600,000
    unsigned short* Wt1  = (unsigned short*)(w + 76800000);      // 65,536
    unsigned short* Wt2  = (unsigned short*)(w + 76865536);      // 65,536
    int* row_ptr  = (int*)(w + 76931072);                        // 400,064 (padded)
    int* csr      = (int*)(w + 77331136);                        // 4,000,000
    int* gcur     = (int*)(w + 81331136);                        // 64*16*4 = 4,096
    int* bstart   = (int*)(w + 81335232);                        // 1,024
    unsigned* bins = (unsigned*)(w + 81336256);                  // 64*18432*4 = 4,718,592 -> end ~86.1 MB

    float* out_mu = (float*)d_out;
    float* out_ls = out_mu + (size_t)NN * OC;

    const int gemm_grid = (NN + 127) / 128;
    const int agg_grid = (NN + 15) / 16;
    const int binA_grid = (NE + EPB - 1) / EPB;

    // ---- CSR build (shared by both layers) ----
    hipMemsetAsync(gcur, 0, NBUCK * GPAD * sizeof(int), stream);
    k_binA<<<binA_grid, 256, 0, stream>>>(src, dst, gcur, bins);
    k_bscan<<<1, 64, 0, stream>>>(gcur, bstart, row_ptr);
    k_binB<<<NBUCK, 512, 0, stream>>>(gcur, bstart, bins, row_ptr, csr);

    // conversions / weight prep
    k_cvt<<<(NN * IC / 8 + 255) / 256, 256, 0, stream>>>(x, xb);
    k_wprep<<<(2 * 128 * 256 + 255) / 256, 256, 0, stream>>>(W1l, W1r, Wml, Wmr, Wsl, Wsr, Wt1, Wt2);

    // layer 1
    k_agg<<<agg_grid, 256, 0, stream>>>(xb, row_ptr, csr, aggb);
    k_gemm<0><<<gemm_grid, 256, 0, stream>>>(aggb, xb, Wt1, b1, nullptr,
                                             hb, nullptr, nullptr);

    // layer 2 (shared aggregation feeds mu and logstd)
    k_agg<<<agg_grid, 256, 0, stream>>>(hb, row_ptr, csr, aggb);
    k_gemm<1><<<gemm_grid, 256, 0, stream>>>(aggb, hb, Wt2, bm, bs,
                                             nullptr, out_mu, out_ls);
}